// Round 1
// baseline (10347.680 us; speedup 1.0000x reference)
//
#include <hip/hip_runtime.h>

typedef unsigned int u32;
typedef unsigned char u8;

#define TSTART 48
#define TEND   49
#define NEGV  -10000.0f

// ---- workspace byte offsets ----
#define O_XG     0ull           // 4096*256*4      = 4,194,304  (x gathered, f16x2, k padded to 512)
#define O_WIHF   4194304ull     // 800*256*4       = 819,200
#define O_WIHB   5013504ull     // 819,200
#define O_WHHF   5832704ull     // 1024*104*4      = 425,984    (rows padded to 1024, k padded to 208)
#define O_WHHB   6258688ull     // 425,984
#define O_BSF    6684672ull     // 3,200
#define O_BSB    6687872ull     // 3,200
#define O_XF     6691072ull     // 4096*800*4      = 13,107,200
#define O_XB     19798272ull    // 13,107,200
#define O_HALL   32905472ull    // 4096*400*4      = 6,553,600
#define O_FEATS  39459072ull    // 4096*50*4       = 819,200
#define O_BP     40278272ull    // 4096*50 u8      = 204,800
#define O_FMAP   40483072ull    // 64*50 u8        = 3,200
#define O_BTAG   40486272ull    // 256
#define O_SCAL   40486528ull    // 64
// total ~40.49 MB

typedef _Float16 h2 __attribute__((ext_vector_type(2)));

__device__ __forceinline__ float fdot2(u32 a, u32 b, float c) {
#if defined(__HIP_DEVICE_COMPILE__) && __has_builtin(__builtin_amdgcn_fdot2)
    return __builtin_amdgcn_fdot2(__builtin_bit_cast(h2, a), __builtin_bit_cast(h2, b), c, false);
#else
    float d;
    asm("v_dot2_f32_f16 %0, %1, %2, %3" : "=v"(d) : "v"(a), "v"(b), "v"(c));
    return d;
#endif
}

__device__ __forceinline__ u32 pack2(float a, float b) {
    u32 lo = __builtin_bit_cast(unsigned short, (_Float16)a);
    u32 hi = __builtin_bit_cast(unsigned short, (_Float16)b);
    return lo | (hi << 16);
}

__device__ __forceinline__ float sigf(float x) { return 1.f / (1.f + __expf(-x)); }
__device__ __forceinline__ float tanhf_(float x) { return 2.f / (1.f + __expf(-2.f * x)) - 1.f; }

// =============== K0: prep (pack f16 weights, gather+pack embeddings, bias sums) ===============
__global__ __launch_bounds__(256) void k_prep(
    const int* __restrict__ ids, const float* __restrict__ emb,
    const float* __restrict__ wihf, const float* __restrict__ wihb,
    const float* __restrict__ whhf, const float* __restrict__ whhb,
    const float* __restrict__ bihf, const float* __restrict__ bhhf,
    const float* __restrict__ bihb, const float* __restrict__ bhhb,
    u32* __restrict__ xg, u32* __restrict__ wif16, u32* __restrict__ wib16,
    u32* __restrict__ whf16, u32* __restrict__ whb16,
    float* __restrict__ bsf, float* __restrict__ bsb)
{
    int idx = blockIdx.x * 256 + threadIdx.x;
    if (idx < 106496) {                               // whh fwd: [1024][104]
        int r = idx / 104, d = idx % 104;
        whf16[idx] = (r < 800 && d < 100) ? pack2(whhf[r*200 + 2*d], whhf[r*200 + 2*d + 1]) : 0u;
    } else if (idx < 212992) {
        int i = idx - 106496; int r = i / 104, d = i % 104;
        whb16[i] = (r < 800 && d < 100) ? pack2(whhb[r*200 + 2*d], whhb[r*200 + 2*d + 1]) : 0u;
    } else if (idx < 417792) {                        // wih fwd: [800][256]
        int i = idx - 212992; int r = i >> 8, d = i & 255;
        wif16[i] = (d < 250) ? pack2(wihf[r*500 + 2*d], wihf[r*500 + 2*d + 1]) : 0u;
    } else if (idx < 622592) {
        int i = idx - 417792; int r = i >> 8, d = i & 255;
        wib16[i] = (d < 250) ? pack2(wihb[r*500 + 2*d], wihb[r*500 + 2*d + 1]) : 0u;
    } else if (idx < 1671168) {                       // xg: [4096][256]
        int i = idx - 622592; int s = i >> 8, d = i & 255;
        long id = ids[s];
        xg[i] = (d < 250) ? pack2(emb[id*500 + 2*d], emb[id*500 + 2*d + 1]) : 0u;
    } else if (idx < 1671968) {
        int j = idx - 1671168; bsf[j] = bihf[j] + bhhf[j];
    } else if (idx < 1672768) {
        int j = idx - 1671968; bsb[j] = bihb[j] + bhhb[j];
    }
}

// =============== K1: input GEMM  xp[s][j] = dot(x[s or rev], w_ih[j]) + bias ===============
// tile 256(M) x 128(N), K = 256 dwords (f16 pairs), 256 threads, micro 16x8
__global__ __launch_bounds__(256, 2) void k_gemm(
    const u32* __restrict__ xg, const u32* __restrict__ wf, const u32* __restrict__ wb,
    const float* __restrict__ bsf, const float* __restrict__ bsb,
    float* __restrict__ xf, float* __restrict__ xb)
{
    int z = blockIdx.z;
    const u32* W = z ? wb : wf;
    const float* bs = z ? bsb : bsf;
    float* out = z ? xb : xf;
    int m0 = blockIdx.x * 256, n0 = blockIdx.y * 128;
    int t = threadIdx.x;

    __shared__ u32 As[16][256];
    __shared__ u32 Bs[16][128];

    float acc[16][8];
#pragma unroll
    for (int m = 0; m < 16; m++)
#pragma unroll
        for (int n = 0; n < 8; n++) acc[m][n] = 0.f;

    int arow = m0 + t; if (z) arow = 4095 - arow;
    const u32* aptr = xg + (size_t)arow * 256;
    int bj = n0 + (t >> 1);
    int ko = (t & 1) * 8;
    const u32* bptr = W + (size_t)bj * 256 + ko;

    int ry = t >> 4, cx = t & 15;

    for (int kc = 0; kc < 16; ++kc) {
        int kd = kc * 16;
        uint4 a0 = *(const uint4*)(aptr + kd);
        uint4 a1 = *(const uint4*)(aptr + kd + 4);
        uint4 a2 = *(const uint4*)(aptr + kd + 8);
        uint4 a3 = *(const uint4*)(aptr + kd + 12);
        uint4 bv0 = {0,0,0,0}, bv1 = {0,0,0,0};
        if (bj < 800) { bv0 = *(const uint4*)(bptr + kd); bv1 = *(const uint4*)(bptr + kd + 4); }
        __syncthreads();
        u32 ad[16] = {a0.x,a0.y,a0.z,a0.w, a1.x,a1.y,a1.z,a1.w,
                      a2.x,a2.y,a2.z,a2.w, a3.x,a3.y,a3.z,a3.w};
#pragma unroll
        for (int i = 0; i < 16; i++) As[i][t] = ad[i];
        u32 bd[8] = {bv0.x,bv0.y,bv0.z,bv0.w, bv1.x,bv1.y,bv1.z,bv1.w};
#pragma unroll
        for (int i = 0; i < 8; i++) Bs[ko + i][t >> 1] = bd[i];
        __syncthreads();
#pragma unroll
        for (int d = 0; d < 16; ++d) {
            const u32* ar = &As[d][ry * 16];
            uint4 x0 = *(const uint4*)(ar);
            uint4 x1 = *(const uint4*)(ar + 4);
            uint4 x2 = *(const uint4*)(ar + 8);
            uint4 x3 = *(const uint4*)(ar + 12);
            const u32* br = &Bs[d][cx * 8];
            uint4 y0 = *(const uint4*)(br);
            uint4 y1 = *(const uint4*)(br + 4);
            u32 am[16] = {x0.x,x0.y,x0.z,x0.w, x1.x,x1.y,x1.z,x1.w,
                          x2.x,x2.y,x2.z,x2.w, x3.x,x3.y,x3.z,x3.w};
            u32 bn[8] = {y0.x,y0.y,y0.z,y0.w, y1.x,y1.y,y1.z,y1.w};
#pragma unroll
            for (int m = 0; m < 16; m++)
#pragma unroll
                for (int n = 0; n < 8; n++)
                    acc[m][n] = fdot2(am[m], bn[n], acc[m][n]);
        }
    }
    int col = n0 + cx * 8;
    if (col < 800) {
        float4 bi0 = *(const float4*)(bs + col);
        float4 bi1 = *(const float4*)(bs + col + 4);
#pragma unroll
        for (int m = 0; m < 16; m++) {
            size_t ro = (size_t)(m0 + ry * 16 + m) * 800 + col;
            float4 o0 = {acc[m][0]+bi0.x, acc[m][1]+bi0.y, acc[m][2]+bi0.z, acc[m][3]+bi0.w};
            float4 o1 = {acc[m][4]+bi1.x, acc[m][5]+bi1.y, acc[m][6]+bi1.z, acc[m][7]+bi1.w};
            *(float4*)(out + ro) = o0;
            *(float4*)(out + ro + 4) = o1;
        }
    }
}

// =============== K2: LSTM recurrence, one block per direction ===============
// 256 threads: thread t = (grp = t>>1, kh = t&1); rows grp*7..grp*7+6 (padded to 896), k-half kh (104 of 208 padded)
__global__ __launch_bounds__(256, 1) void k_lstm(
    const u32* __restrict__ whf, const u32* __restrict__ whb,
    const float* __restrict__ xf, const float* __restrict__ xb,
    const float* __restrict__ h0, const float* __restrict__ c0,
    float* __restrict__ hall)
{
    int dir = blockIdx.x, t = threadIdx.x;
    const u32* Wh = dir ? whb : whf;
    const float* xp = dir ? xb : xf;
    int kh = t & 1, grp = t >> 1;
    int r0 = grp * 7;

    uint4 w[7][13];
#pragma unroll
    for (int m = 0; m < 7; m++) {
        const uint4* p = (const uint4*)(Wh + (size_t)(r0 + m) * 104 + kh * 52);
#pragma unroll
        for (int c = 0; c < 13; c++) w[m][c] = p[c];
    }

    __shared__ __align__(16) _Float16 hsh[208];
    __shared__ float gsh[800];

    float cst = 0.f, hv = 0.f;
    if (t < 200) { cst = c0[dir*200 + t]; hv = h0[dir*200 + t]; hsh[t] = (_Float16)hv; }
    if (t >= 200 && t < 208) hsh[t] = (_Float16)0.f;

    float xr[7];
#pragma unroll
    for (int m = 0; m < 7; m++) {
        int r = r0 + m;
        xr[m] = (kh == 0 && r < 800) ? xp[r] : 0.f;
    }
    __syncthreads();

    const uint4* hp = (const uint4*)(hsh + kh * 104);

    for (int s = 0; s < 4096; ++s) {
        float acc[7];
#pragma unroll
        for (int m = 0; m < 7; m++) acc[m] = xr[m];
        if (s + 1 < 4096) {
#pragma unroll
            for (int m = 0; m < 7; m++) {
                int r = r0 + m;
                xr[m] = (kh == 0 && r < 800) ? xp[(size_t)(s + 1) * 800 + r] : 0.f;
            }
        }
#pragma unroll
        for (int c = 0; c < 13; c++) {
            uint4 hb = hp[c];
#pragma unroll
            for (int m = 0; m < 7; m++) {
                acc[m] = fdot2(w[m][c].x, hb.x, acc[m]);
                acc[m] = fdot2(w[m][c].y, hb.y, acc[m]);
                acc[m] = fdot2(w[m][c].z, hb.z, acc[m]);
                acc[m] = fdot2(w[m][c].w, hb.w, acc[m]);
            }
        }
#pragma unroll
        for (int m = 0; m < 7; m++) acc[m] += __shfl_xor(acc[m], 1);
        if (kh == 0) {
#pragma unroll
            for (int m = 0; m < 7; m++) { int r = r0 + m; if (r < 800) gsh[r] = acc[m]; }
        }
        __syncthreads();
        if (t < 200) {
            float gi = gsh[t], gf = gsh[200 + t], gg = gsh[400 + t], go = gsh[600 + t];
            float is = sigf(gi), fs = sigf(gf), gt = tanhf_(gg), os = sigf(go);
            cst = fs * cst + is * gt;
            hv = os * tanhf_(cst);
            int orow = dir ? (4095 - s) : s;
            hall[(size_t)orow * 400 + dir * 200 + t] = hv;
            hsh[t] = (_Float16)hv;
        }
        __syncthreads();
    }
}

// =============== K3: final linear  feats = hcat @ lw.T + lb ===============
__global__ __launch_bounds__(256, 1) void k_linear(
    const float* __restrict__ hall, const float* __restrict__ lw,
    const float* __restrict__ lb, float* __restrict__ feats)
{
    int b = blockIdx.x, t = threadIdx.x;
    int j = t & 63, sl = t >> 6;
    int s0 = b * 32 + sl * 8;
    bool act = j < 50;
    int jj = act ? j : 0;
    float acc[8];
#pragma unroll
    for (int m = 0; m < 8; m++) acc[m] = act ? lb[j] : 0.f;
    for (int kc = 0; kc < 4; kc++) {
        float4 wv[25];
        const float4* wp = (const float4*)(lw + (size_t)jj * 400 + kc * 100);
#pragma unroll
        for (int c = 0; c < 25; c++) wv[c] = wp[c];
#pragma unroll
        for (int m = 0; m < 8; m++) {
            const float4* hq = (const float4*)(hall + (size_t)(s0 + m) * 400 + kc * 100);
            float a = 0.f;
#pragma unroll
            for (int c = 0; c < 25; c++) {
                float4 h4 = hq[c];
                a = fmaf(h4.x, wv[c].x, a); a = fmaf(h4.y, wv[c].y, a);
                a = fmaf(h4.z, wv[c].z, a); a = fmaf(h4.w, wv[c].w, a);
            }
            acc[m] += a;
        }
    }
    if (act) {
#pragma unroll
        for (int m = 0; m < 8; m++) feats[(size_t)(s0 + m) * 50 + j] = acc[m];
    }
}

// =============== K4: CRF forward (block0) + Viterbi (block1) + gold score (block2) ===============
__global__ __launch_bounds__(512) void k_crf(
    const float* __restrict__ feats, const float* __restrict__ trans,
    const int* __restrict__ tags, u8* __restrict__ bp, float* __restrict__ scal)
{
    __shared__ float tl[2500];
    __shared__ float al[2][64];
    __shared__ float red[512];
    int t = threadIdx.x;
    for (int i = t; i < 2500; i += 512) tl[i] = trans[i];
    __syncthreads();

    int role = blockIdx.x;
    if (role == 2) {        // gold score
        float loc = 0.f;
        for (int i = t; i < 4096; i += 512) {
            int prev = i ? tags[i - 1] : TSTART;
            int cur = tags[i];
            loc += tl[prev * 50 + cur] + feats[(size_t)i * 50 + cur];
        }
        red[t] = loc; __syncthreads();
        for (int w = 256; w > 0; w >>= 1) { if (t < w) red[t] += red[t + w]; __syncthreads(); }
        if (t == 0) scal[1] = red[0] + tl[tags[4095] * 50 + TEND];
        return;
    }

    int j = t >> 3, q = t & 7;
    bool jv = j < 50;
    float Tc[7];
#pragma unroll
    for (int r = 0; r < 7; r++) {
        int i = q + 8 * r;
        Tc[r] = (jv && i < 50) ? tl[i * 50 + j] : 0.f;
    }
    if (t < 64) al[0][t] = (t == TSTART) ? 0.f : NEGV;
    __syncthreads();

    int cur = 0;
    float fcur = 0.f;
    if (q == 0 && jv) fcur = feats[j];

    if (role == 0) {        // CRF forward (logsumexp)
        for (int s = 0; s < 4096; ++s) {
            float fnext = 0.f;
            if (s + 1 < 4096 && q == 0 && jv) fnext = feats[(size_t)(s + 1) * 50 + j];
            float v[7]; float m = -3.0e38f;
#pragma unroll
            for (int r = 0; r < 7; r++) {
                int i = q + 8 * r;
                float vv = (i < 50) ? al[cur][i] + Tc[r] : -3.0e38f;
                v[r] = vv; m = fmaxf(m, vv);
            }
            m = fmaxf(m, __shfl_xor(m, 1));
            m = fmaxf(m, __shfl_xor(m, 2));
            m = fmaxf(m, __shfl_xor(m, 4));
            float sum = 0.f;
#pragma unroll
            for (int r = 0; r < 7; r++) {
                int i = q + 8 * r;
                if (i < 50) sum += __expf(v[r] - m);
            }
            sum += __shfl_xor(sum, 1);
            sum += __shfl_xor(sum, 2);
            sum += __shfl_xor(sum, 4);
            if (q == 0 && jv) al[cur ^ 1][j] = fcur + m + __logf(sum);
            fcur = fnext; cur ^= 1;
            __syncthreads();
        }
        if (t == 0) {
            float m = -3.0e38f;
            for (int i = 0; i < 50; i++) m = fmaxf(m, al[cur][i] + tl[i * 50 + TEND]);
            float sm = 0.f;
            for (int i = 0; i < 50; i++) sm += __expf(al[cur][i] + tl[i * 50 + TEND] - m);
            scal[0] = m + __logf(sm);
        }
    } else {                // Viterbi
        for (int s = 0; s < 4096; ++s) {
            float fnext = 0.f;
            if (s + 1 < 4096 && q == 0 && jv) fnext = feats[(size_t)(s + 1) * 50 + j];
            float m = -3.0e38f; int mi = 63;
#pragma unroll
            for (int r = 0; r < 7; r++) {
                int i = q + 8 * r;
                float vv = (i < 50) ? al[cur][i] + Tc[r] : -3.0e38f;
                if (vv > m) { m = vv; mi = i; }
            }
#pragma unroll
            for (int k = 1; k < 8; k <<= 1) {
                float om = __shfl_xor(m, k); int oi = __shfl_xor(mi, k);
                if (om > m || (om == m && oi < mi)) { m = om; mi = oi; }
            }
            if (q == 0 && jv) {
                al[cur ^ 1][j] = m + fcur;
                bp[(size_t)s * 50 + j] = (u8)mi;
            }
            fcur = fnext; cur ^= 1;
            __syncthreads();
        }
        if (t == 0) {
            float best = -3.0e38f; int bi = 0;
            for (int i = 0; i < 50; i++) {
                float f = al[cur][i] + tl[i * 50 + TEND];
                if (f > best) { best = f; bi = i; }
            }
            ((int*)scal)[2] = bi;
        }
    }
}

// =============== K5: per-chunk composed backtrace maps (64 chunks of 64 steps) ===============
__global__ __launch_bounds__(64) void k_maps(const u8* __restrict__ bp, u8* __restrict__ fmap)
{
    __shared__ __align__(4) u8 bpl[3200];
    int c = blockIdx.x, t = threadIdx.x;
    const u32* src = (const u32*)(bp + (size_t)c * 3200);
    u32* dst = (u32*)bpl;
    for (int i = t; i < 800; i += 64) dst[i] = src[i];
    __syncthreads();
    if (t < 50) {
        int y = t;
        for (int k = 63; k >= 0; --k) y = bpl[k * 50 + y];
        fmap[c * 50 + t] = (u8)y;
    }
}

// =============== K6: boundary chase + loss ===============
__global__ __launch_bounds__(64) void k_chase(const u8* __restrict__ fmap, const float* __restrict__ scal,
                                              u8* __restrict__ btag, float* __restrict__ dout)
{
    __shared__ __align__(4) u8 fl[3200];
    int t = threadIdx.x;
    for (int i = t; i < 800; i += 64) ((u32*)fl)[i] = ((const u32*)fmap)[i];
    __syncthreads();
    if (t == 0) {
        int b = ((const int*)scal)[2];
        btag[63] = (u8)b;
        for (int c = 63; c >= 1; --c) { b = fl[c * 50 + b]; btag[c - 1] = (u8)b; }
        dout[4096] = scal[0] - scal[1];
    }
}

// =============== K7: per-chunk path replay ===============
__global__ __launch_bounds__(64) void k_replay(const u8* __restrict__ bp, const u8* __restrict__ btag,
                                               float* __restrict__ dout)
{
    __shared__ __align__(4) u8 bpl[3200];
    int c = blockIdx.x, t = threadIdx.x;
    for (int i = t; i < 800; i += 64) ((u32*)bpl)[i] = ((const u32*)(bp + (size_t)c * 3200))[i];
    __syncthreads();
    if (t == 0) {
        int y = btag[c];
        dout[c * 64 + 63] = (float)y;
        for (int k = 62; k >= 0; --k) {
            y = bpl[(k + 1) * 50 + y];
            dout[c * 64 + k] = (float)y;
        }
    }
}

extern "C" void kernel_launch(void* const* d_in, const int* in_sizes, int n_in,
                              void* d_out, int out_size, void* d_ws, size_t ws_size,
                              hipStream_t stream)
{
    const int*   ids   = (const int*)d_in[0];
    const int*   tags  = (const int*)d_in[1];
    const float* emb   = (const float*)d_in[2];
    const float* wihf  = (const float*)d_in[3];
    const float* whhf  = (const float*)d_in[4];
    const float* bihf  = (const float*)d_in[5];
    const float* bhhf  = (const float*)d_in[6];
    const float* wihb  = (const float*)d_in[7];
    const float* whhb  = (const float*)d_in[8];
    const float* bihb  = (const float*)d_in[9];
    const float* bhhb  = (const float*)d_in[10];
    const float* lw    = (const float*)d_in[11];
    const float* lb    = (const float*)d_in[12];
    const float* trans = (const float*)d_in[13];
    const float* h0    = (const float*)d_in[14];
    const float* c0    = (const float*)d_in[15];
    float* dout = (float*)d_out;

    char* w = (char*)d_ws;
    u32*   xg    = (u32*)(w + O_XG);
    u32*   wif16 = (u32*)(w + O_WIHF);
    u32*   wib16 = (u32*)(w + O_WIHB);
    u32*   whf16 = (u32*)(w + O_WHHF);
    u32*   whb16 = (u32*)(w + O_WHHB);
    float* bsf   = (float*)(w + O_BSF);
    float* bsb   = (float*)(w + O_BSB);
    float* xf    = (float*)(w + O_XF);
    float* xb    = (float*)(w + O_XB);
    float* hall  = (float*)(w + O_HALL);
    float* feats = (float*)(w + O_FEATS);
    u8*    bp    = (u8*)(w + O_BP);
    u8*    fmap  = (u8*)(w + O_FMAP);
    u8*    btag  = (u8*)(w + O_BTAG);
    float* scal  = (float*)(w + O_SCAL);

    k_prep<<<6535, 256, 0, stream>>>(ids, emb, wihf, wihb, whhf, whhb,
                                     bihf, bhhf, bihb, bhhb,
                                     xg, wif16, wib16, whf16, whb16, bsf, bsb);
    k_gemm<<<dim3(16, 7, 2), 256, 0, stream>>>(xg, wif16, wib16, bsf, bsb, xf, xb);
    k_lstm<<<2, 256, 0, stream>>>(whf16, whb16, xf, xb, h0, c0, hall);
    k_linear<<<128, 256, 0, stream>>>(hall, lw, lb, feats);
    k_crf<<<3, 512, 0, stream>>>(feats, trans, tags, bp, scal);
    k_maps<<<64, 64, 0, stream>>>(bp, fmap);
    k_chase<<<1, 64, 0, stream>>>(fmap, scal, btag, dout);
    k_replay<<<64, 64, 0, stream>>>(bp, btag, dout);
}

// Round 2
// 8148.248 us; speedup vs baseline: 1.2699x; 1.2699x over previous
//
#include <hip/hip_runtime.h>

typedef unsigned int u32;
typedef unsigned char u8;

#define TSTART 48
#define TEND   49
#define NEGV  -10000.0f

// ---- workspace byte offsets ----
#define O_XG     0ull            // 4096*256*4   = 4,194,304 (x gathered f16x2, k 250->256)
#define O_WIHF   4194304ull      // 800*256*4    = 819,200
#define O_WIHB   5013504ull      // 819,200
#define O_WHHF   5832704ull      // 512 chunks * 176 dwords * 4 = 360,448 (per-thread packed)
#define O_WHHB   6193152ull      // 360,448
#define O_BSF    6553600ull      // 3,200
#define O_BSB    6556800ull      // 3,200
#define O_LWP    6560000ull      // 50*200*4 = 40,000 (linear_w packed f16 pairs)
#define O_XF     6600000ull      // 4096*800*4 = 13,107,200
#define O_XB     19707200ull     // 13,107,200
#define O_HT     32814400ull     // 200 rows * 4096 * 4 = 3,276,800 (h pairs f16x2, [pair][seq])
#define O_FEATS  36091200ull     // 4096*50*4 = 819,200
#define O_BP     36910400ull     // 204,800
#define O_FMAP   37115200ull     // 3,200
#define O_BTAG   37118400ull     // 256
#define O_SCAL   37118656ull     // 64

typedef _Float16 h2 __attribute__((ext_vector_type(2)));

__device__ __forceinline__ float fdot2(u32 a, u32 b, float c) {
#if defined(__HIP_DEVICE_COMPILE__) && __has_builtin(__builtin_amdgcn_fdot2)
    return __builtin_amdgcn_fdot2(__builtin_bit_cast(h2, a), __builtin_bit_cast(h2, b), c, false);
#else
    float d;
    asm("v_dot2_f32_f16 %0, %1, %2, %3" : "=v"(d) : "v"(a), "v"(b), "v"(c));
    return d;
#endif
}

__device__ __forceinline__ u32 pack2(float a, float b) {
    u32 lo = __builtin_bit_cast(unsigned short, (_Float16)a);
    u32 hi = __builtin_bit_cast(unsigned short, (_Float16)b);
    return lo | (hi << 16);
}

__device__ __forceinline__ float sigf(float x) { return 1.f / (1.f + __expf(-x)); }
__device__ __forceinline__ float tanhf_(float x) { return 2.f / (1.f + __expf(-2.f * x)) - 1.f; }

// element ranges in k_prep's flat index space (dword elements)
#define PA_END   90112      // whf packed
#define PB_END   180224     // whb packed
#define PC_END   385024     // wihf
#define PD_END   589824     // wihb
#define PE_END   1638400    // xg
#define PF_END   1648400    // lwpack
#define PG_END   1649200    // bsf
#define PH_END   1650000    // bsb

// whh per-thread packed layout: chunk = thread id t in [0,512) = rgrp*4+ks.
// chunk holds 176 dwords: off<168: q=off>>2,e=off&3,c4=q/7,m=q%7 -> row=rgrp*7+m, kd=ks*25+c4*4+e
//              off in [168,175): m=off-168, kd=ks*25+24 ; off=175: zero pad
__global__ __launch_bounds__(256) void k_prep(
    const int* __restrict__ ids, const float* __restrict__ emb,
    const float* __restrict__ wihf, const float* __restrict__ wihb,
    const float* __restrict__ whhf, const float* __restrict__ whhb,
    const float* __restrict__ bihf, const float* __restrict__ bhhf,
    const float* __restrict__ bihb, const float* __restrict__ bhhb,
    const float* __restrict__ lw,
    u32* __restrict__ xg, u32* __restrict__ wif16, u32* __restrict__ wib16,
    u32* __restrict__ whf16, u32* __restrict__ whb16, u32* __restrict__ lwp,
    float* __restrict__ bsf, float* __restrict__ bsb)
{
    int idx = blockIdx.x * 256 + threadIdx.x;
    if (idx < PB_END) {                               // packed whh (both dirs)
        int dirb = (idx >= PA_END);
        int i = idx - (dirb ? PA_END : 0);
        const float* whh = dirb ? whhb : whhf;
        u32* dst = dirb ? whb16 : whf16;
        int chunk = i / 176, off = i % 176;
        int rgrp = chunk >> 2, ks = chunk & 3;
        u32 v = 0;
        if (off < 175) {
            int m, kd;
            if (off < 168) { int q = off >> 2, e = off & 3; kd = ks * 25 + (q / 7) * 4 + e; m = q % 7; }
            else           { m = off - 168; kd = ks * 25 + 24; }
            int row = rgrp * 7 + m;
            if (row < 800) v = pack2(whh[row * 200 + 2 * kd], whh[row * 200 + 2 * kd + 1]);
        }
        dst[i] = v;
    } else if (idx < PD_END) {                        // wih: [800][256]
        int dirb = (idx >= PC_END);
        int i = idx - (dirb ? PC_END : PB_END);
        const float* wih = dirb ? wihb : wihf;
        u32* dst = dirb ? wib16 : wif16;
        int r = i >> 8, d = i & 255;
        dst[i] = (d < 250) ? pack2(wih[r * 500 + 2 * d], wih[r * 500 + 2 * d + 1]) : 0u;
    } else if (idx < PE_END) {                        // xg: [4096][256]
        int i = idx - PD_END; int s = i >> 8, d = i & 255;
        long id = ids[s];
        xg[i] = (d < 250) ? pack2(emb[id * 500 + 2 * d], emb[id * 500 + 2 * d + 1]) : 0u;
    } else if (idx < PF_END) {                        // lwpack [50][200]
        int i = idx - PE_END; int tag = i / 200, u = i % 200;
        lwp[i] = pack2(lw[tag * 400 + 2 * u], lw[tag * 400 + 2 * u + 1]);
    } else if (idx < PG_END) {
        int j = idx - PF_END; bsf[j] = bihf[j] + bhhf[j];
    } else if (idx < PH_END) {
        int j = idx - PG_END; bsb[j] = bihb[j] + bhhb[j];
    }
}

// =============== K1: input GEMM  xp[s][j] = dot(x[s or rev], w_ih[j]) + bias ===============
__global__ __launch_bounds__(256, 2) void k_gemm(
    const u32* __restrict__ xg, const u32* __restrict__ wf, const u32* __restrict__ wb,
    const float* __restrict__ bsf, const float* __restrict__ bsb,
    float* __restrict__ xf, float* __restrict__ xb)
{
    int z = blockIdx.z;
    const u32* W = z ? wb : wf;
    const float* bs = z ? bsb : bsf;
    float* out = z ? xb : xf;
    int m0 = blockIdx.x * 256, n0 = blockIdx.y * 128;
    int t = threadIdx.x;

    __shared__ u32 As[16][256];
    __shared__ u32 Bs[16][128];

    float acc[16][8];
#pragma unroll
    for (int m = 0; m < 16; m++)
#pragma unroll
        for (int n = 0; n < 8; n++) acc[m][n] = 0.f;

    int arow = m0 + t; if (z) arow = 4095 - arow;
    const u32* aptr = xg + (size_t)arow * 256;
    int bj = n0 + (t >> 1);
    int ko = (t & 1) * 8;
    const u32* bptr = W + (size_t)bj * 256 + ko;

    int ry = t >> 4, cx = t & 15;

    for (int kc = 0; kc < 16; ++kc) {
        int kd = kc * 16;
        uint4 a0 = *(const uint4*)(aptr + kd);
        uint4 a1 = *(const uint4*)(aptr + kd + 4);
        uint4 a2 = *(const uint4*)(aptr + kd + 8);
        uint4 a3 = *(const uint4*)(aptr + kd + 12);
        uint4 bv0 = {0,0,0,0}, bv1 = {0,0,0,0};
        if (bj < 800) { bv0 = *(const uint4*)(bptr + kd); bv1 = *(const uint4*)(bptr + kd + 4); }
        __syncthreads();
        u32 ad[16] = {a0.x,a0.y,a0.z,a0.w, a1.x,a1.y,a1.z,a1.w,
                      a2.x,a2.y,a2.z,a2.w, a3.x,a3.y,a3.z,a3.w};
#pragma unroll
        for (int i = 0; i < 16; i++) As[i][t] = ad[i];
        u32 bd[8] = {bv0.x,bv0.y,bv0.z,bv0.w, bv1.x,bv1.y,bv1.z,bv1.w};
#pragma unroll
        for (int i = 0; i < 8; i++) Bs[ko + i][t >> 1] = bd[i];
        __syncthreads();
#pragma unroll
        for (int d = 0; d < 16; ++d) {
            const u32* ar = &As[d][ry * 16];
            uint4 x0 = *(const uint4*)(ar);
            uint4 x1 = *(const uint4*)(ar + 4);
            uint4 x2 = *(const uint4*)(ar + 8);
            uint4 x3 = *(const uint4*)(ar + 12);
            const u32* br = &Bs[d][cx * 8];
            uint4 y0 = *(const uint4*)(br);
            uint4 y1 = *(const uint4*)(br + 4);
            u32 am[16] = {x0.x,x0.y,x0.z,x0.w, x1.x,x1.y,x1.z,x1.w,
                          x2.x,x2.y,x2.z,x2.w, x3.x,x3.y,x3.z,x3.w};
            u32 bn[8] = {y0.x,y0.y,y0.z,y0.w, y1.x,y1.y,y1.z,y1.w};
#pragma unroll
            for (int m = 0; m < 16; m++)
#pragma unroll
                for (int n = 0; n < 8; n++)
                    acc[m][n] = fdot2(am[m], bn[n], acc[m][n]);
        }
    }
    int col = n0 + cx * 8;
    if (col < 800) {
        float4 bi0 = *(const float4*)(bs + col);
        float4 bi1 = *(const float4*)(bs + col + 4);
#pragma unroll
        for (int m = 0; m < 16; m++) {
            size_t ro = (size_t)(m0 + ry * 16 + m) * 800 + col;
            float4 o0 = {acc[m][0]+bi0.x, acc[m][1]+bi0.y, acc[m][2]+bi0.z, acc[m][3]+bi0.w};
            float4 o1 = {acc[m][4]+bi1.x, acc[m][5]+bi1.y, acc[m][6]+bi1.z, acc[m][7]+bi1.w};
            *(float4*)(out + ro) = o0;
            *(float4*)(out + ro + 4) = o1;
        }
    }
}

// =============== K2: LSTM recurrence. 512 threads: t = rgrp*4+ks ===============
// rgrp in [0,128): rows rgrp*7..+6 (padded 896); ks in [0,4): k-dwords ks*25..+24 of 100.
// Weights per thread: 42 uint4 + 7 dwords = 175 VGPRs, per-thread-contiguous in memory.
__global__ __launch_bounds__(512, 2) void k_lstm(
    const u32* __restrict__ whf, const u32* __restrict__ whb,
    const float* __restrict__ xf, const float* __restrict__ xb,
    const float* __restrict__ h0, const float* __restrict__ c0,
    u32* __restrict__ hallT)
{
    int dir = blockIdx.x, t = threadIdx.x;
    const u32* Wh = dir ? whb : whf;
    const float* xp = dir ? xb : xf;
    int ks = t & 3, rgrp = t >> 2, r0 = rgrp * 7;

    uint4 w4[42];
    u32 w1[7];
    {
        const uint4* p = (const uint4*)(Wh + (size_t)t * 176);
#pragma unroll
        for (int i = 0; i < 42; i++) w4[i] = p[i];
        const u32* p1 = Wh + (size_t)t * 176 + 168;
#pragma unroll
        for (int m = 0; m < 7; m++) w1[m] = p1[m];
    }

    __shared__ __align__(16) u32 hsh[112];   // 4 slices * 28 dwords (25 used)
    __shared__ float gsh[800];

    if (t < 112) hsh[t] = 0u;
    __syncthreads();

    float cst = 0.f;
    int haddr = 0;
    if (t < 200) {
        cst = c0[dir * 200 + t];
        int u = t >> 1;
        haddr = (u / 25) * 28 + (u % 25);
        if (!(t & 1)) hsh[haddr] = pack2(h0[dir * 200 + t], h0[dir * 200 + t + 1]);
    }
    __syncthreads();

    const u32* hbase = hsh + ks * 28;
    float xr[4];
    u32 hbuf[8];

    for (int s = 0; s < 4096; ++s) {
        // issue x loads for THIS step early: latency hides under the dot work,
        // so barrier A's vmcnt drain is free.
        if (t < 200) {
            size_t xo = (size_t)s * 800 + t;
            xr[0] = xp[xo]; xr[1] = xp[xo + 200]; xr[2] = xp[xo + 400]; xr[3] = xp[xo + 600];
        }
        // flush previous 8-step h batch (store-ack also drains for free at barrier A)
        if ((s & 7) == 0 && s && t < 200 && !(t & 1)) {
            int sdone = s - 1;
            int base = dir ? (4095 - sdone) : (sdone - 7);
            uint4* dst = (uint4*)(hallT + (size_t)(dir * 100 + (t >> 1)) * 4096 + base);
            uint4 v0 = {hbuf[0], hbuf[1], hbuf[2], hbuf[3]};
            uint4 v1 = {hbuf[4], hbuf[5], hbuf[6], hbuf[7]};
            dst[0] = v0; dst[1] = v1;
        }

        float acc[7];
#pragma unroll
        for (int m = 0; m < 7; m++) acc[m] = 0.f;
#pragma unroll
        for (int c4 = 0; c4 < 6; c4++) {
            uint4 hb = *(const uint4*)(hbase + c4 * 4);
#pragma unroll
            for (int m = 0; m < 7; m++) {
                uint4 wv = w4[c4 * 7 + m];
                acc[m] = fdot2(wv.x, hb.x, acc[m]);
                acc[m] = fdot2(wv.y, hb.y, acc[m]);
                acc[m] = fdot2(wv.z, hb.z, acc[m]);
                acc[m] = fdot2(wv.w, hb.w, acc[m]);
            }
        }
        {
            u32 hb1 = hbase[24];
#pragma unroll
            for (int m = 0; m < 7; m++) acc[m] = fdot2(w1[m], hb1, acc[m]);
        }
#pragma unroll
        for (int m = 0; m < 7; m++) {
            acc[m] += __shfl_xor(acc[m], 1);
            acc[m] += __shfl_xor(acc[m], 2);
        }
        if (ks == 0) {
#pragma unroll
            for (int m = 0; m < 7; m++) { int r = r0 + m; if (r < 800) gsh[r] = acc[m]; }
        }
        __syncthreads();   // A: gsh ready, x loads drained (hidden)

        if (t < 200) {
            float gi = gsh[t] + xr[0], gf = gsh[200 + t] + xr[1];
            float gg = gsh[400 + t] + xr[2], go = gsh[600 + t] + xr[3];
            float is = sigf(gi), fs = sigf(gf), gt = tanhf_(gg), os = sigf(go);
            cst = fs * cst + is * gt;
            float hv = os * tanhf_(cst);
            float hq = __shfl_xor(hv, 1);
            if (!(t & 1)) {
                u32 pv = pack2(hv, hq);
                hsh[haddr] = pv;
                int slot = dir ? (7 - (s & 7)) : (s & 7);
                hbuf[slot] = pv;
            }
        }
        __syncthreads();   // B: hsh ready for next step (lgkm-only drain, cheap)
    }
    // final batch (steps 4088..4095)
    if (t < 200 && !(t & 1)) {
        int base = dir ? 0 : 4088;
        uint4* dst = (uint4*)(hallT + (size_t)(dir * 100 + (t >> 1)) * 4096 + base);
        uint4 v0 = {hbuf[0], hbuf[1], hbuf[2], hbuf[3]};
        uint4 v1 = {hbuf[4], hbuf[5], hbuf[6], hbuf[7]};
        dst[0] = v0; dst[1] = v1;
    }
}

// =============== K3: final linear, one block per sequence position ===============
__global__ __launch_bounds__(64) void k_linear(
    const u32* __restrict__ hallT, const u32* __restrict__ lwp,
    const float* __restrict__ lb, float* __restrict__ feats)
{
    int s = blockIdx.x, t = threadIdx.x;
    __shared__ __align__(16) u32 hc[200];
#pragma unroll
    for (int k = 0; k < 4; k++) {
        int u = t + 64 * k;
        if (u < 200) hc[u] = hallT[(size_t)u * 4096 + s];
    }
    __syncthreads();
    if (t < 50) {
        const uint4* wp = (const uint4*)(lwp + t * 200);
        const uint4* hp = (const uint4*)hc;
        float acc = lb[t];
#pragma unroll 10
        for (int c = 0; c < 50; c++) {
            uint4 wv = wp[c]; uint4 hv = hp[c];
            acc = fdot2(wv.x, hv.x, acc); acc = fdot2(wv.y, hv.y, acc);
            acc = fdot2(wv.z, hv.z, acc); acc = fdot2(wv.w, hv.w, acc);
        }
        feats[(size_t)s * 50 + t] = acc;
    }
}

// =============== K4: CRF forward (block0) + Viterbi (block1) + gold score (block2) ===============
__global__ __launch_bounds__(512) void k_crf(
    const float* __restrict__ feats, const float* __restrict__ trans,
    const int* __restrict__ tags, u8* __restrict__ bp, float* __restrict__ scal)
{
    __shared__ float tl[2500];
    __shared__ float al[2][64];
    __shared__ float red[512];
    int t = threadIdx.x;
    for (int i = t; i < 2500; i += 512) tl[i] = trans[i];
    __syncthreads();

    int role = blockIdx.x;
    if (role == 2) {        // gold score
        float loc = 0.f;
        for (int i = t; i < 4096; i += 512) {
            int prev = i ? tags[i - 1] : TSTART;
            int cur = tags[i];
            loc += tl[prev * 50 + cur] + feats[(size_t)i * 50 + cur];
        }
        red[t] = loc; __syncthreads();
        for (int w = 256; w > 0; w >>= 1) { if (t < w) red[t] += red[t + w]; __syncthreads(); }
        if (t == 0) scal[1] = red[0] + tl[tags[4095] * 50 + TEND];
        return;
    }

    int j = t >> 3, q = t & 7;
    bool jv = j < 50;
    float Tc[7];
#pragma unroll
    for (int r = 0; r < 7; r++) {
        int i = q + 8 * r;
        Tc[r] = (jv && i < 50) ? tl[i * 50 + j] : 0.f;
    }
    if (t < 64) al[0][t] = (t == TSTART) ? 0.f : NEGV;
    __syncthreads();

    int cur = 0;
    float fcur = 0.f;
    if (q == 0 && jv) fcur = feats[j];

    if (role == 0) {        // CRF forward (logsumexp)
        for (int s = 0; s < 4096; ++s) {
            float fnext = 0.f;
            if (s + 1 < 4096 && q == 0 && jv) fnext = feats[(size_t)(s + 1) * 50 + j];
            float v[7]; float m = -3.0e38f;
#pragma unroll
            for (int r = 0; r < 7; r++) {
                int i = q + 8 * r;
                float vv = (i < 50) ? al[cur][i] + Tc[r] : -3.0e38f;
                v[r] = vv; m = fmaxf(m, vv);
            }
            m = fmaxf(m, __shfl_xor(m, 1));
            m = fmaxf(m, __shfl_xor(m, 2));
            m = fmaxf(m, __shfl_xor(m, 4));
            float sum = 0.f;
#pragma unroll
            for (int r = 0; r < 7; r++) {
                int i = q + 8 * r;
                if (i < 50) sum += __expf(v[r] - m);
            }
            sum += __shfl_xor(sum, 1);
            sum += __shfl_xor(sum, 2);
            sum += __shfl_xor(sum, 4);
            if (q == 0 && jv) al[cur ^ 1][j] = fcur + m + __logf(sum);
            fcur = fnext; cur ^= 1;
            __syncthreads();
        }
        if (t == 0) {
            float m = -3.0e38f;
            for (int i = 0; i < 50; i++) m = fmaxf(m, al[cur][i] + tl[i * 50 + TEND]);
            float sm = 0.f;
            for (int i = 0; i < 50; i++) sm += __expf(al[cur][i] + tl[i * 50 + TEND] - m);
            scal[0] = m + __logf(sm);
        }
    } else {                // Viterbi
        for (int s = 0; s < 4096; ++s) {
            float fnext = 0.f;
            if (s + 1 < 4096 && q == 0 && jv) fnext = feats[(size_t)(s + 1) * 50 + j];
            float m = -3.0e38f; int mi = 63;
#pragma unroll
            for (int r = 0; r < 7; r++) {
                int i = q + 8 * r;
                float vv = (i < 50) ? al[cur][i] + Tc[r] : -3.0e38f;
                if (vv > m) { m = vv; mi = i; }
            }
#pragma unroll
            for (int k = 1; k < 8; k <<= 1) {
                float om = __shfl_xor(m, k); int oi = __shfl_xor(mi, k);
                if (om > m || (om == m && oi < mi)) { m = om; mi = oi; }
            }
            if (q == 0 && jv) {
                al[cur ^ 1][j] = m + fcur;
                bp[(size_t)s * 50 + j] = (u8)mi;
            }
            fcur = fnext; cur ^= 1;
            __syncthreads();
        }
        if (t == 0) {
            float best = -3.0e38f; int bi = 0;
            for (int i = 0; i < 50; i++) {
                float f = al[cur][i] + tl[i * 50 + TEND];
                if (f > best) { best = f; bi = i; }
            }
            ((int*)scal)[2] = bi;
        }
    }
}

// =============== K5: per-chunk composed backtrace maps ===============
__global__ __launch_bounds__(64) void k_maps(const u8* __restrict__ bp, u8* __restrict__ fmap)
{
    __shared__ __align__(4) u8 bpl[3200];
    int c = blockIdx.x, t = threadIdx.x;
    const u32* src = (const u32*)(bp + (size_t)c * 3200);
    u32* dst = (u32*)bpl;
    for (int i = t; i < 800; i += 64) dst[i] = src[i];
    __syncthreads();
    if (t < 50) {
        int y = t;
        for (int k = 63; k >= 0; --k) y = bpl[k * 50 + y];
        fmap[c * 50 + t] = (u8)y;
    }
}

// =============== K6: boundary chase + loss ===============
__global__ __launch_bounds__(64) void k_chase(const u8* __restrict__ fmap, const float* __restrict__ scal,
                                              u8* __restrict__ btag, float* __restrict__ dout)
{
    __shared__ __align__(4) u8 fl[3200];
    int t = threadIdx.x;
    for (int i = t; i < 800; i += 64) ((u32*)fl)[i] = ((const u32*)fmap)[i];
    __syncthreads();
    if (t == 0) {
        int b = ((const int*)scal)[2];
        btag[63] = (u8)b;
        for (int c = 63; c >= 1; --c) { b = fl[c * 50 + b]; btag[c - 1] = (u8)b; }
        dout[4096] = scal[0] - scal[1];
    }
}

// =============== K7: per-chunk path replay ===============
__global__ __launch_bounds__(64) void k_replay(const u8* __restrict__ bp, const u8* __restrict__ btag,
                                               float* __restrict__ dout)
{
    __shared__ __align__(4) u8 bpl[3200];
    int c = blockIdx.x, t = threadIdx.x;
    for (int i = t; i < 800; i += 64) ((u32*)bpl)[i] = ((const u32*)(bp + (size_t)c * 3200))[i];
    __syncthreads();
    if (t == 0) {
        int y = btag[c];
        dout[c * 64 + 63] = (float)y;
        for (int k = 62; k >= 0; --k) {
            y = bpl[(k + 1) * 50 + y];
            dout[c * 64 + k] = (float)y;
        }
    }
}

extern "C" void kernel_launch(void* const* d_in, const int* in_sizes, int n_in,
                              void* d_out, int out_size, void* d_ws, size_t ws_size,
                              hipStream_t stream)
{
    const int*   ids   = (const int*)d_in[0];
    const int*   tags  = (const int*)d_in[1];
    const float* emb   = (const float*)d_in[2];
    const float* wihf  = (const float*)d_in[3];
    const float* whhf  = (const float*)d_in[4];
    const float* bihf  = (const float*)d_in[5];
    const float* bhhf  = (const float*)d_in[6];
    const float* wihb  = (const float*)d_in[7];
    const float* whhb  = (const float*)d_in[8];
    const float* bihb  = (const float*)d_in[9];
    const float* bhhb  = (const float*)d_in[10];
    const float* lw    = (const float*)d_in[11];
    const float* lb    = (const float*)d_in[12];
    const float* trans = (const float*)d_in[13];
    const float* h0    = (const float*)d_in[14];
    const float* c0    = (const float*)d_in[15];
    float* dout = (float*)d_out;

    char* w = (char*)d_ws;
    u32*   xg    = (u32*)(w + O_XG);
    u32*   wif16 = (u32*)(w + O_WIHF);
    u32*   wib16 = (u32*)(w + O_WIHB);
    u32*   whf16 = (u32*)(w + O_WHHF);
    u32*   whb16 = (u32*)(w + O_WHHB);
    float* bsf   = (float*)(w + O_BSF);
    float* bsb   = (float*)(w + O_BSB);
    u32*   lwp   = (u32*)(w + O_LWP);
    float* xf    = (float*)(w + O_XF);
    float* xb    = (float*)(w + O_XB);
    u32*   hallT = (u32*)(w + O_HT);
    float* feats = (float*)(w + O_FEATS);
    u8*    bp    = (u8*)(w + O_BP);
    u8*    fmap  = (u8*)(w + O_FMAP);
    u8*    btag  = (u8*)(w + O_BTAG);
    float* scal  = (float*)(w + O_SCAL);

    k_prep<<<6446, 256, 0, stream>>>(ids, emb, wihf, wihb, whhf, whhb,
                                     bihf, bhhf, bihb, bhhb, lw,
                                     xg, wif16, wib16, whf16, whb16, lwp, bsf, bsb);
    k_gemm<<<dim3(16, 7, 2), 256, 0, stream>>>(xg, wif16, wib16, bsf, bsb, xf, xb);
    k_lstm<<<2, 512, 0, stream>>>(whf16, whb16, xf, xb, h0, c0, hallT);
    k_linear<<<4096, 64, 0, stream>>>(hallT, lwp, lb, feats);
    k_crf<<<3, 512, 0, stream>>>(feats, trans, tags, bp, scal);
    k_maps<<<64, 64, 0, stream>>>(bp, fmap);
    k_chase<<<1, 64, 0, stream>>>(fmap, scal, btag, dout);
    k_replay<<<64, 64, 0, stream>>>(bp, btag, dout);
}

// Round 3
// 7560.943 us; speedup vs baseline: 1.3686x; 1.0777x over previous
//
#include <hip/hip_runtime.h>

typedef unsigned int u32;
typedef unsigned char u8;

#define TSTART 48
#define TEND   49
#define NEGV  -10000.0f

// ---- workspace byte offsets ----
#define O_XG     0ull            // 4096*256*4   = 4,194,304 (x gathered f16x2, k 250->256)
#define O_WIHF   4194304ull      // 800*256*4    = 819,200
#define O_WIHB   5013504ull      // 819,200
#define O_WHHF   5832704ull      // 512 chunks * 176 dwords * 4 = 360,448 (per-thread packed)
#define O_WHHB   6193152ull      // 360,448
#define O_BSF    6553600ull      // 3,200
#define O_BSB    6556800ull      // 3,200
#define O_LWP    6560000ull      // 50*200*4 = 40,000 (linear_w packed f16 pairs)
#define O_XF     6600000ull      // 4096*800*4 = 13,107,200
#define O_XB     19707200ull     // 13,107,200
#define O_HT     32814400ull     // 200 rows * 4096 * 4 = 3,276,800 (h pairs f16x2, [pair][seq])
#define O_FEATS  36091200ull     // 4096*50*4 = 819,200
#define O_BP     36910400ull     // 204,800
#define O_FMAP   37115200ull     // 3,200
#define O_BTAG   37118400ull     // 256
#define O_SCAL   37118656ull     // 64

typedef _Float16 h2 __attribute__((ext_vector_type(2)));

__device__ __forceinline__ float fdot2(u32 a, u32 b, float c) {
#if defined(__HIP_DEVICE_COMPILE__) && __has_builtin(__builtin_amdgcn_fdot2)
    return __builtin_amdgcn_fdot2(__builtin_bit_cast(h2, a), __builtin_bit_cast(h2, b), c, false);
#else
    float d;
    asm("v_dot2_f32_f16 %0, %1, %2, %3" : "=v"(d) : "v"(a), "v"(b), "v"(c));
    return d;
#endif
}

__device__ __forceinline__ u32 pack2(float a, float b) {
    u32 lo = __builtin_bit_cast(unsigned short, (_Float16)a);
    u32 hi = __builtin_bit_cast(unsigned short, (_Float16)b);
    return lo | (hi << 16);
}

__device__ __forceinline__ float sigf(float x) { return 1.f / (1.f + __expf(-x)); }
__device__ __forceinline__ float tanhf_(float x) { return 2.f / (1.f + __expf(-2.f * x)) - 1.f; }

// element ranges in k_prep's flat index space (dword elements)
#define PA_END   90112      // whf packed
#define PB_END   180224     // whb packed
#define PC_END   385024     // wihf
#define PD_END   589824     // wihb
#define PE_END   1638400    // xg
#define PF_END   1648400    // lwpack
#define PG_END   1649200    // bsf
#define PH_END   1650000    // bsb

// whh per-thread packed layout: chunk = thread id t in [0,512) = rgrp*4+ks.
// chunk holds 176 dwords: off<168: q=off>>2,e=off&3,c4=q/7,m=q%7 -> row=rgrp*7+m, kd=ks*25+c4*4+e
//              off in [168,175): m=off-168, kd=ks*25+24 ; off=175: zero pad
__global__ __launch_bounds__(256) void k_prep(
    const int* __restrict__ ids, const float* __restrict__ emb,
    const float* __restrict__ wihf, const float* __restrict__ wihb,
    const float* __restrict__ whhf, const float* __restrict__ whhb,
    const float* __restrict__ bihf, const float* __restrict__ bhhf,
    const float* __restrict__ bihb, const float* __restrict__ bhhb,
    const float* __restrict__ lw,
    u32* __restrict__ xg, u32* __restrict__ wif16, u32* __restrict__ wib16,
    u32* __restrict__ whf16, u32* __restrict__ whb16, u32* __restrict__ lwp,
    float* __restrict__ bsf, float* __restrict__ bsb)
{
    int idx = blockIdx.x * 256 + threadIdx.x;
    if (idx < PB_END) {                               // packed whh (both dirs)
        int dirb = (idx >= PA_END);
        int i = idx - (dirb ? PA_END : 0);
        const float* whh = dirb ? whhb : whhf;
        u32* dst = dirb ? whb16 : whf16;
        int chunk = i / 176, off = i % 176;
        int rgrp = chunk >> 2, ks = chunk & 3;
        u32 v = 0;
        if (off < 175) {
            int m, kd;
            if (off < 168) { int q = off >> 2, e = off & 3; kd = ks * 25 + (q / 7) * 4 + e; m = q % 7; }
            else           { m = off - 168; kd = ks * 25 + 24; }
            int row = rgrp * 7 + m;
            if (row < 800) v = pack2(whh[row * 200 + 2 * kd], whh[row * 200 + 2 * kd + 1]);
        }
        dst[i] = v;
    } else if (idx < PD_END) {                        // wih: [800][256]
        int dirb = (idx >= PC_END);
        int i = idx - (dirb ? PC_END : PB_END);
        const float* wih = dirb ? wihb : wihf;
        u32* dst = dirb ? wib16 : wif16;
        int r = i >> 8, d = i & 255;
        dst[i] = (d < 250) ? pack2(wih[r * 500 + 2 * d], wih[r * 500 + 2 * d + 1]) : 0u;
    } else if (idx < PE_END) {                        // xg: [4096][256]
        int i = idx - PD_END; int s = i >> 8, d = i & 255;
        long id = ids[s];
        xg[i] = (d < 250) ? pack2(emb[id * 500 + 2 * d], emb[id * 500 + 2 * d + 1]) : 0u;
    } else if (idx < PF_END) {                        // lwpack [50][200]
        int i = idx - PE_END; int tag = i / 200, u = i % 200;
        lwp[i] = pack2(lw[tag * 400 + 2 * u], lw[tag * 400 + 2 * u + 1]);
    } else if (idx < PG_END) {
        int j = idx - PF_END; bsf[j] = bihf[j] + bhhf[j];
    } else if (idx < PH_END) {
        int j = idx - PG_END; bsb[j] = bihb[j] + bhhb[j];
    }
}

// =============== K1: input GEMM  xp[s][j] = dot(x[s or rev], w_ih[j]) + bias ===============
__global__ __launch_bounds__(256, 2) void k_gemm(
    const u32* __restrict__ xg, const u32* __restrict__ wf, const u32* __restrict__ wb,
    const float* __restrict__ bsf, const float* __restrict__ bsb,
    float* __restrict__ xf, float* __restrict__ xb)
{
    int z = blockIdx.z;
    const u32* W = z ? wb : wf;
    const float* bs = z ? bsb : bsf;
    float* out = z ? xb : xf;
    int m0 = blockIdx.x * 256, n0 = blockIdx.y * 128;
    int t = threadIdx.x;

    __shared__ u32 As[16][256];
    __shared__ u32 Bs[16][128];

    float acc[16][8];
#pragma unroll
    for (int m = 0; m < 16; m++)
#pragma unroll
        for (int n = 0; n < 8; n++) acc[m][n] = 0.f;

    int arow = m0 + t; if (z) arow = 4095 - arow;
    const u32* aptr = xg + (size_t)arow * 256;
    int bj = n0 + (t >> 1);
    int ko = (t & 1) * 8;
    const u32* bptr = W + (size_t)bj * 256 + ko;

    int ry = t >> 4, cx = t & 15;

    for (int kc = 0; kc < 16; ++kc) {
        int kd = kc * 16;
        uint4 a0 = *(const uint4*)(aptr + kd);
        uint4 a1 = *(const uint4*)(aptr + kd + 4);
        uint4 a2 = *(const uint4*)(aptr + kd + 8);
        uint4 a3 = *(const uint4*)(aptr + kd + 12);
        uint4 bv0 = {0,0,0,0}, bv1 = {0,0,0,0};
        if (bj < 800) { bv0 = *(const uint4*)(bptr + kd); bv1 = *(const uint4*)(bptr + kd + 4); }
        __syncthreads();
        u32 ad[16] = {a0.x,a0.y,a0.z,a0.w, a1.x,a1.y,a1.z,a1.w,
                      a2.x,a2.y,a2.z,a2.w, a3.x,a3.y,a3.z,a3.w};
#pragma unroll
        for (int i = 0; i < 16; i++) As[i][t] = ad[i];
        u32 bd[8] = {bv0.x,bv0.y,bv0.z,bv0.w, bv1.x,bv1.y,bv1.z,bv1.w};
#pragma unroll
        for (int i = 0; i < 8; i++) Bs[ko + i][t >> 1] = bd[i];
        __syncthreads();
#pragma unroll
        for (int d = 0; d < 16; ++d) {
            const u32* ar = &As[d][ry * 16];
            uint4 x0 = *(const uint4*)(ar);
            uint4 x1 = *(const uint4*)(ar + 4);
            uint4 x2 = *(const uint4*)(ar + 8);
            uint4 x3 = *(const uint4*)(ar + 12);
            const u32* br = &Bs[d][cx * 8];
            uint4 y0 = *(const uint4*)(br);
            uint4 y1 = *(const uint4*)(br + 4);
            u32 am[16] = {x0.x,x0.y,x0.z,x0.w, x1.x,x1.y,x1.z,x1.w,
                          x2.x,x2.y,x2.z,x2.w, x3.x,x3.y,x3.z,x3.w};
            u32 bn[8] = {y0.x,y0.y,y0.z,y0.w, y1.x,y1.y,y1.z,y1.w};
#pragma unroll
            for (int m = 0; m < 16; m++)
#pragma unroll
                for (int n = 0; n < 8; n++)
                    acc[m][n] = fdot2(am[m], bn[n], acc[m][n]);
        }
    }
    int col = n0 + cx * 8;
    if (col < 800) {
        float4 bi0 = *(const float4*)(bs + col);
        float4 bi1 = *(const float4*)(bs + col + 4);
#pragma unroll
        for (int m = 0; m < 16; m++) {
            size_t ro = (size_t)(m0 + ry * 16 + m) * 800 + col;
            float4 o0 = {acc[m][0]+bi0.x, acc[m][1]+bi0.y, acc[m][2]+bi0.z, acc[m][3]+bi0.w};
            float4 o1 = {acc[m][4]+bi1.x, acc[m][5]+bi1.y, acc[m][6]+bi1.z, acc[m][7]+bi1.w};
            *(float4*)(out + ro) = o0;
            *(float4*)(out + ro + 4) = o1;
        }
    }
}

// =============== K2: LSTM recurrence. 512 threads: t = rgrp*4+ks ===============
// rgrp in [0,128): rows rgrp*7..+6 (padded 896); ks in [0,4): k-dwords ks*25..+24 of 100.
// 175 weight dwords per thread held in NAMED registers (no arrays -> no alloca/spill path).
// amdgpu_waves_per_eu(2,2): pin occupancy target to 2 waves/EU -> full 256-VGPR budget.

#define LOAD_WROW(c) \
    uint4 W##c##0 = p[(c)*7+0], W##c##1 = p[(c)*7+1], W##c##2 = p[(c)*7+2], \
          W##c##3 = p[(c)*7+3], W##c##4 = p[(c)*7+4], W##c##5 = p[(c)*7+5], \
          W##c##6 = p[(c)*7+6];

#define DOTQ(Wv, A) \
    A = fdot2(Wv.x, hb.x, A); A = fdot2(Wv.y, hb.y, A); \
    A = fdot2(Wv.z, hb.z, A); A = fdot2(Wv.w, hb.w, A);

#define DOT_BLOCK(c) { \
    uint4 hb = *(const uint4*)(hbase + (c)*4); \
    DOTQ(W##c##0, acc0) DOTQ(W##c##1, acc1) DOTQ(W##c##2, acc2) DOTQ(W##c##3, acc3) \
    DOTQ(W##c##4, acc4) DOTQ(W##c##5, acc5) DOTQ(W##c##6, acc6) }

#define REDUCE(A) A += __shfl_xor(A, 1); A += __shfl_xor(A, 2);

__global__ __launch_bounds__(512)
__attribute__((amdgpu_waves_per_eu(2, 2)))
void k_lstm(
    const u32* __restrict__ whf, const u32* __restrict__ whb,
    const float* __restrict__ xf, const float* __restrict__ xb,
    const float* __restrict__ h0, const float* __restrict__ c0,
    u32* __restrict__ hallT)
{
    int dir = blockIdx.x, t = threadIdx.x;
    const u32* Wh = dir ? whb : whf;
    const float* xp = dir ? xb : xf;
    int ks = t & 3, rgrp = t >> 2, r0 = rgrp * 7;

    const uint4* p = (const uint4*)(Wh + (size_t)t * 176);
    LOAD_WROW(0) LOAD_WROW(1) LOAD_WROW(2) LOAD_WROW(3) LOAD_WROW(4) LOAD_WROW(5)
    const u32* p1 = Wh + (size_t)t * 176 + 168;
    u32 U0 = p1[0], U1 = p1[1], U2 = p1[2], U3 = p1[3], U4 = p1[4], U5 = p1[5], U6 = p1[6];

    __shared__ __align__(16) u32 hsh[112];   // 4 slices * 28 dwords (25 used)
    __shared__ float gsh[800];
    __shared__ u32 hstage[800];              // [8 steps][100 pairs]

    if (t < 112) hsh[t] = 0u;
    __syncthreads();

    float cst = 0.f;
    int haddr = 0;
    if (t < 200) {
        cst = c0[dir * 200 + t];
        int u = t >> 1;
        haddr = (u / 25) * 28 + (u % 25);
        if (!(t & 1)) hsh[haddr] = pack2(h0[dir * 200 + t], h0[dir * 200 + t + 1]);
    }
    __syncthreads();

    const u32* hbase = hsh + ks * 28;

    for (int s = 0; s < 4096; ++s) {
        // x loads for THIS step issued early: latency hides under dot work,
        // so barrier A's vmcnt drain is free.
        float xr0 = 0.f, xr1 = 0.f, xr2 = 0.f, xr3 = 0.f;
        if (t < 200) {
            size_t xo = (size_t)s * 800 + t;
            xr0 = xp[xo]; xr1 = xp[xo + 200]; xr2 = xp[xo + 400]; xr3 = xp[xo + 600];
        }
        // flush previous 8-step h batch from LDS stage (store-ack drains with x loads)
        if ((s & 7) == 0 && s && t < 100) {
            int s0 = s - 8;
            u32 a0 = hstage[t],       a1 = hstage[100 + t], a2 = hstage[200 + t], a3 = hstage[300 + t];
            u32 a4 = hstage[400 + t], a5 = hstage[500 + t], a6 = hstage[600 + t], a7 = hstage[700 + t];
            uint4* dst;
            uint4 v0, v1;
            if (dir == 0) {
                dst = (uint4*)(hallT + (size_t)t * 4096 + s0);
                v0 = (uint4){a0, a1, a2, a3}; v1 = (uint4){a4, a5, a6, a7};
            } else {
                dst = (uint4*)(hallT + (size_t)(100 + t) * 4096 + (4088 - s0));
                v0 = (uint4){a7, a6, a5, a4}; v1 = (uint4){a3, a2, a1, a0};
            }
            dst[0] = v0; dst[1] = v1;
        }

        float acc0 = 0.f, acc1 = 0.f, acc2 = 0.f, acc3 = 0.f, acc4 = 0.f, acc5 = 0.f, acc6 = 0.f;
        DOT_BLOCK(0) DOT_BLOCK(1) DOT_BLOCK(2) DOT_BLOCK(3) DOT_BLOCK(4) DOT_BLOCK(5)
        {
            u32 hb1 = hbase[24];
            acc0 = fdot2(U0, hb1, acc0); acc1 = fdot2(U1, hb1, acc1);
            acc2 = fdot2(U2, hb1, acc2); acc3 = fdot2(U3, hb1, acc3);
            acc4 = fdot2(U4, hb1, acc4); acc5 = fdot2(U5, hb1, acc5);
            acc6 = fdot2(U6, hb1, acc6);
        }
        REDUCE(acc0) REDUCE(acc1) REDUCE(acc2) REDUCE(acc3) REDUCE(acc4) REDUCE(acc5) REDUCE(acc6)
        if (ks == 0 && r0 < 800) {
            gsh[r0] = acc0;
            if (r0 + 1 < 800) gsh[r0 + 1] = acc1;
            if (r0 + 2 < 800) gsh[r0 + 2] = acc2;
            if (r0 + 3 < 800) gsh[r0 + 3] = acc3;
            if (r0 + 4 < 800) gsh[r0 + 4] = acc4;
            if (r0 + 5 < 800) gsh[r0 + 5] = acc5;
            if (r0 + 6 < 800) gsh[r0 + 6] = acc6;
        }
        __syncthreads();   // A: gsh ready, x loads + h stores drained (hidden)

        if (t < 200) {
            float gi = gsh[t] + xr0, gf = gsh[200 + t] + xr1;
            float gg = gsh[400 + t] + xr2, go = gsh[600 + t] + xr3;
            float is = sigf(gi), fs = sigf(gf), gt = tanhf_(gg), os = sigf(go);
            cst = fs * cst + is * gt;
            float hv = os * tanhf_(cst);
            float hq = __shfl_xor(hv, 1);
            if (!(t & 1)) {
                u32 pv = pack2(hv, hq);
                hsh[haddr] = pv;
                hstage[(s & 7) * 100 + (t >> 1)] = pv;
            }
        }
        __syncthreads();   // B: hsh/hstage ready for next step (lgkm-only, cheap)
    }
    // final batch (steps 4088..4095)
    if (t < 100) {
        u32 a0 = hstage[t],       a1 = hstage[100 + t], a2 = hstage[200 + t], a3 = hstage[300 + t];
        u32 a4 = hstage[400 + t], a5 = hstage[500 + t], a6 = hstage[600 + t], a7 = hstage[700 + t];
        uint4* dst;
        uint4 v0, v1;
        if (dir == 0) {
            dst = (uint4*)(hallT + (size_t)t * 4096 + 4088);
            v0 = (uint4){a0, a1, a2, a3}; v1 = (uint4){a4, a5, a6, a7};
        } else {
            dst = (uint4*)(hallT + (size_t)(100 + t) * 4096);
            v0 = (uint4){a7, a6, a5, a4}; v1 = (uint4){a3, a2, a1, a0};
        }
        dst[0] = v0; dst[1] = v1;
    }
}

// =============== K3: final linear, one block per sequence position ===============
__global__ __launch_bounds__(64) void k_linear(
    const u32* __restrict__ hallT, const u32* __restrict__ lwp,
    const float* __restrict__ lb, float* __restrict__ feats)
{
    int s = blockIdx.x, t = threadIdx.x;
    __shared__ __align__(16) u32 hc[200];
#pragma unroll
    for (int k = 0; k < 4; k++) {
        int u = t + 64 * k;
        if (u < 200) hc[u] = hallT[(size_t)u * 4096 + s];
    }
    __syncthreads();
    if (t < 50) {
        const uint4* wp = (const uint4*)(lwp + t * 200);
        const uint4* hp = (const uint4*)hc;
        float acc = lb[t];
#pragma unroll 10
        for (int c = 0; c < 50; c++) {
            uint4 wv = wp[c]; uint4 hv = hp[c];
            acc = fdot2(wv.x, hv.x, acc); acc = fdot2(wv.y, hv.y, acc);
            acc = fdot2(wv.z, hv.z, acc); acc = fdot2(wv.w, hv.w, acc);
        }
        feats[(size_t)s * 50 + t] = acc;
    }
}

// =============== K4: CRF forward (block0) + Viterbi (block1) + gold score (block2) ===============
__global__ __launch_bounds__(512) void k_crf(
    const float* __restrict__ feats, const float* __restrict__ trans,
    const int* __restrict__ tags, u8* __restrict__ bp, float* __restrict__ scal)
{
    __shared__ float tl[2500];
    __shared__ float al[2][64];
    __shared__ float red[512];
    int t = threadIdx.x;
    for (int i = t; i < 2500; i += 512) tl[i] = trans[i];
    __syncthreads();

    int role = blockIdx.x;
    if (role == 2) {        // gold score
        float loc = 0.f;
        for (int i = t; i < 4096; i += 512) {
            int prev = i ? tags[i - 1] : TSTART;
            int cur = tags[i];
            loc += tl[prev * 50 + cur] + feats[(size_t)i * 50 + cur];
        }
        red[t] = loc; __syncthreads();
        for (int w = 256; w > 0; w >>= 1) { if (t < w) red[t] += red[t + w]; __syncthreads(); }
        if (t == 0) scal[1] = red[0] + tl[tags[4095] * 50 + TEND];
        return;
    }

    int j = t >> 3, q = t & 7;
    bool jv = j < 50;
    float Tc[7];
#pragma unroll
    for (int r = 0; r < 7; r++) {
        int i = q + 8 * r;
        Tc[r] = (jv && i < 50) ? tl[i * 50 + j] : 0.f;
    }
    if (t < 64) al[0][t] = (t == TSTART) ? 0.f : NEGV;
    __syncthreads();

    int cur = 0;
    float fcur = 0.f;
    if (q == 0 && jv) fcur = feats[j];

    if (role == 0) {        // CRF forward (logsumexp)
        for (int s = 0; s < 4096; ++s) {
            float fnext = 0.f;
            if (s + 1 < 4096 && q == 0 && jv) fnext = feats[(size_t)(s + 1) * 50 + j];
            float v[7]; float m = -3.0e38f;
#pragma unroll
            for (int r = 0; r < 7; r++) {
                int i = q + 8 * r;
                float vv = (i < 50) ? al[cur][i] + Tc[r] : -3.0e38f;
                v[r] = vv; m = fmaxf(m, vv);
            }
            m = fmaxf(m, __shfl_xor(m, 1));
            m = fmaxf(m, __shfl_xor(m, 2));
            m = fmaxf(m, __shfl_xor(m, 4));
            float sum = 0.f;
#pragma unroll
            for (int r = 0; r < 7; r++) {
                int i = q + 8 * r;
                if (i < 50) sum += __expf(v[r] - m);
            }
            sum += __shfl_xor(sum, 1);
            sum += __shfl_xor(sum, 2);
            sum += __shfl_xor(sum, 4);
            if (q == 0 && jv) al[cur ^ 1][j] = fcur + m + __logf(sum);
            fcur = fnext; cur ^= 1;
            __syncthreads();
        }
        if (t == 0) {
            float m = -3.0e38f;
            for (int i = 0; i < 50; i++) m = fmaxf(m, al[cur][i] + tl[i * 50 + TEND]);
            float sm = 0.f;
            for (int i = 0; i < 50; i++) sm += __expf(al[cur][i] + tl[i * 50 + TEND] - m);
            scal[0] = m + __logf(sm);
        }
    } else {                // Viterbi
        for (int s = 0; s < 4096; ++s) {
            float fnext = 0.f;
            if (s + 1 < 4096 && q == 0 && jv) fnext = feats[(size_t)(s + 1) * 50 + j];
            float m = -3.0e38f; int mi = 63;
#pragma unroll
            for (int r = 0; r < 7; r++) {
                int i = q + 8 * r;
                float vv = (i < 50) ? al[cur][i] + Tc[r] : -3.0e38f;
                if (vv > m) { m = vv; mi = i; }
            }
#pragma unroll
            for (int k = 1; k < 8; k <<= 1) {
                float om = __shfl_xor(m, k); int oi = __shfl_xor(mi, k);
                if (om > m || (om == m && oi < mi)) { m = om; mi = oi; }
            }
            if (q == 0 && jv) {
                al[cur ^ 1][j] = m + fcur;
                bp[(size_t)s * 50 + j] = (u8)mi;
            }
            fcur = fnext; cur ^= 1;
            __syncthreads();
        }
        if (t == 0) {
            float best = -3.0e38f; int bi = 0;
            for (int i = 0; i < 50; i++) {
                float f = al[cur][i] + tl[i * 50 + TEND];
                if (f > best) { best = f; bi = i; }
            }
            ((int*)scal)[2] = bi;
        }
    }
}

// =============== K5: per-chunk composed backtrace maps ===============
__global__ __launch_bounds__(64) void k_maps(const u8* __restrict__ bp, u8* __restrict__ fmap)
{
    __shared__ __align__(4) u8 bpl[3200];
    int c = blockIdx.x, t = threadIdx.x;
    const u32* src = (const u32*)(bp + (size_t)c * 3200);
    u32* dst = (u32*)bpl;
    for (int i = t; i < 800; i += 64) dst[i] = src[i];
    __syncthreads();
    if (t < 50) {
        int y = t;
        for (int k = 63; k >= 0; --k) y = bpl[k * 50 + y];
        fmap[c * 50 + t] = (u8)y;
    }
}

// =============== K6: boundary chase + loss ===============
__global__ __launch_bounds__(64) void k_chase(const u8* __restrict__ fmap, const float* __restrict__ scal,
                                              u8* __restrict__ btag, float* __restrict__ dout)
{
    __shared__ __align__(4) u8 fl[3200];
    int t = threadIdx.x;
    for (int i = t; i < 800; i += 64) ((u32*)fl)[i] = ((const u32*)fmap)[i];
    __syncthreads();
    if (t == 0) {
        int b = ((const int*)scal)[2];
        btag[63] = (u8)b;
        for (int c = 63; c >= 1; --c) { b = fl[c * 50 + b]; btag[c - 1] = (u8)b; }
        dout[4096] = scal[0] - scal[1];
    }
}

// =============== K7: per-chunk path replay ===============
__global__ __launch_bounds__(64) void k_replay(const u8* __restrict__ bp, const u8* __restrict__ btag,
                                               float* __restrict__ dout)
{
    __shared__ __align__(4) u8 bpl[3200];
    int c = blockIdx.x, t = threadIdx.x;
    for (int i = t; i < 800; i += 64) ((u32*)bpl)[i] = ((const u32*)(bp + (size_t)c * 3200))[i];
    __syncthreads();
    if (t == 0) {
        int y = btag[c];
        dout[c * 64 + 63] = (float)y;
        for (int k = 62; k >= 0; --k) {
            y = bpl[(k + 1) * 50 + y];
            dout[c * 64 + k] = (float)y;
        }
    }
}

extern "C" void kernel_launch(void* const* d_in, const int* in_sizes, int n_in,
                              void* d_out, int out_size, void* d_ws, size_t ws_size,
                              hipStream_t stream)
{
    const int*   ids   = (const int*)d_in[0];
    const int*   tags  = (const int*)d_in[1];
    const float* emb   = (const float*)d_in[2];
    const float* wihf  = (const float*)d_in[3];
    const float* whhf  = (const float*)d_in[4];
    const float* bihf  = (const float*)d_in[5];
    const float* bhhf  = (const float*)d_in[6];
    const float* wihb  = (const float*)d_in[7];
    const float* whhb  = (const float*)d_in[8];
    const float* bihb  = (const float*)d_in[9];
    const float* bhhb  = (const float*)d_in[10];
    const float* lw    = (const float*)d_in[11];
    const float* lb    = (const float*)d_in[12];
    const float* trans = (const float*)d_in[13];
    const float* h0    = (const float*)d_in[14];
    const float* c0    = (const float*)d_in[15];
    float* dout = (float*)d_out;

    char* w = (char*)d_ws;
    u32*   xg    = (u32*)(w + O_XG);
    u32*   wif16 = (u32*)(w + O_WIHF);
    u32*   wib16 = (u32*)(w + O_WIHB);
    u32*   whf16 = (u32*)(w + O_WHHF);
    u32*   whb16 = (u32*)(w + O_WHHB);
    float* bsf   = (float*)(w + O_BSF);
    float* bsb   = (float*)(w + O_BSB);
    u32*   lwp   = (u32*)(w + O_LWP);
    float* xf    = (float*)(w + O_XF);
    float* xb    = (float*)(w + O_XB);
    u32*   hallT = (u32*)(w + O_HT);
    float* feats = (float*)(w + O_FEATS);
    u8*    bp    = (u8*)(w + O_BP);
    u8*    fmap  = (u8*)(w + O_FMAP);
    u8*    btag  = (u8*)(w + O_BTAG);
    float* scal  = (float*)(w + O_SCAL);

    k_prep<<<6446, 256, 0, stream>>>(ids, emb, wihf, wihb, whhf, whhb,
                                     bihf, bhhf, bihb, bhhb, lw,
                                     xg, wif16, wib16, whf16, whb16, lwp, bsf, bsb);
    k_gemm<<<dim3(16, 7, 2), 256, 0, stream>>>(xg, wif16, wib16, bsf, bsb, xf, xb);
    k_lstm<<<2, 512, 0, stream>>>(whf16, whb16, xf, xb, h0, c0, hallT);
    k_linear<<<4096, 64, 0, stream>>>(hallT, lwp, lb, feats);
    k_crf<<<3, 512, 0, stream>>>(feats, trans, tags, bp, scal);
    k_maps<<<64, 64, 0, stream>>>(bp, fmap);
    k_chase<<<1, 64, 0, stream>>>(fmap, scal, btag, dout);
    k_replay<<<64, 64, 0, stream>>>(bp, btag, dout);
}